// Round 11
// baseline (227.716 us; speedup 1.0000x reference)
//
#include <hip/hip_runtime.h>
#include <hip/hip_bf16.h>

// Problem dims (fixed by reference setup)
#define B_   16
#define N_   8
#define C_   512
#define D_   768
#define HH   64
#define WW   64
#define HW   4096          // 64*64 pixels per batch

typedef __bf16 bf16;
typedef __attribute__((ext_vector_type(8))) __bf16 bf16x8;
typedef __attribute__((ext_vector_type(4))) __bf16 bf16x4;
typedef __attribute__((ext_vector_type(4))) float  f32x4;

// ---------------------------------------------------------------------------
// K_pre (single launch, all independent pieces):
// Blocks 0..127  : (b,n) pair. Q[n,c] in-register (wave-per-c dot over d,
//                  we preloaded in 12 regs/lane, coalesced wq_w rows,
//                  shfl-reduce) -> Ql LDS; then Qkb[b,n,m] =
//                  bf16((Ql·wk_w[:,m])/sqrt(768)) coalesced. Also zeroes
//                  padding row n+8.
// Blocks 128..639: W2[o,c] = wo_w[o,:]·wv_w[:,c] (bf16), (8 o x 64 c) per
//                  block, K split over 4 waves + LDS reduce; b2 on cc==0.
__global__ __launch_bounds__(512) void k_pre(const float* __restrict__ se,
                                             const float* __restrict__ weights,
                                             const float* __restrict__ wq_w,
                                             const float* __restrict__ wq_b,
                                             const float* __restrict__ wk_w,
                                             const float* __restrict__ wo_w,
                                             const float* __restrict__ wv_w,
                                             const float* __restrict__ wv_b,
                                             bf16* __restrict__ Qkb,
                                             bf16* __restrict__ W2,
                                             float* __restrict__ b2) {
    __shared__ __align__(16) unsigned char smem[12288];
    int tid = threadIdx.x;
    int blk = blockIdx.x;
    if (blk < 128) {
        int b = blk >> 3, n = blk & 7;
        float* we = (float*)smem;                     // [768]
        float* Ql = (float*)(smem + 3072);            // [512]
        // phase 1: we[d] = se[b,n,d] * weights[n]
        float wt = weights[n];
        const float* se_row = se + (size_t)(b * N_ + n) * D_;
        for (int i = tid; i < D_; i += 512) we[i] = se_row[i] * wt;
        __syncthreads();
        int wid = tid >> 6, lane = tid & 63;
        // lane-local we registers: d = k*256 + lane*4 + j
        f32x4 wer[3];
        #pragma unroll
        for (int k = 0; k < 3; ++k)
            wer[k] = *(const f32x4*)(we + k * 256 + lane * 4);
        // phase 2: Q[c] for c in wave's 64-chunk; coalesced wq_w row reads
        int c0 = wid * 64;
        #pragma unroll 2
        for (int cc = 0; cc < 64; ++cc) {
            int c = c0 + cc;
            const float* row = wq_w + (size_t)c * D_ + lane * 4;
            float dot = 0.f;
            #pragma unroll
            for (int k = 0; k < 3; ++k) {
                f32x4 v = *(const f32x4*)(row + k * 256);
                dot += v[0]*wer[k][0] + v[1]*wer[k][1]
                     + v[2]*wer[k][2] + v[3]*wer[k][3];
            }
            #pragma unroll
            for (int off = 1; off <= 32; off <<= 1) dot += __shfl_xor(dot, off);
            if (lane == 0) Ql[c] = dot + wq_b[c];
        }
        __syncthreads();
        // phase 3: Qk[m] = sum_o Ql[o]*wk_w[o,m]; coalesced wk_w rows
        int m = tid;
        float a0 = 0.f, a1 = 0.f, a2 = 0.f, a3 = 0.f;
        #pragma unroll 2
        for (int o = 0; o < C_; o += 4) {
            a0 = fmaf(Ql[o + 0], wk_w[(size_t)(o + 0) * C_ + m], a0);
            a1 = fmaf(Ql[o + 1], wk_w[(size_t)(o + 1) * C_ + m], a1);
            a2 = fmaf(Ql[o + 2], wk_w[(size_t)(o + 2) * C_ + m], a2);
            a3 = fmaf(Ql[o + 3], wk_w[(size_t)(o + 3) * C_ + m], a3);
        }
        Qkb[((size_t)b * 16 + n) * C_ + m] =
            (bf16)((((a0 + a1) + (a2 + a3)) * 3.6084391824351615e-2f));
        Qkb[((size_t)b * 16 + 8 + n) * C_ + m] = (bf16)0.f;  // padding row
    } else {
        int bb = blk - 128;                           // 0..511
        int og = bb >> 3, cc = bb & 7;                // 64 o-groups x 8 c-chunks
        int cl = tid & 63, kq = tid >> 6;             // wave = k-quarter
        int kqq = kq & 3;                             // 8 waves -> 4 quarters x2
        int khalf = kq >> 2;                          // split 128 into 2x64
        int c  = cc * 64 + cl;
        const float* wo = wo_w + (size_t)og * 8 * C_; // uniform rows
        float a[8] = {};
        #pragma unroll 4
        for (int i = 0; i < 64; ++i) {
            int k = kqq * 128 + khalf * 64 + i;
            float v = wv_w[(size_t)k * C_ + c];       // coalesced 256B/wave
            #pragma unroll
            for (int j = 0; j < 8; ++j)
                a[j] = fmaf(wo[(size_t)j * C_ + k], v, a[j]);  // s_load
        }
        float (*part)[8][64] = (float(*)[8][64])smem;
        #pragma unroll
        for (int j = 0; j < 8; ++j) {
            if (khalf) part[kqq][j][cl] = a[j];
        }
        __syncthreads();
        if (khalf == 0) {
            #pragma unroll
            for (int j = 0; j < 8; ++j) part[kqq][j][cl] += a[j];
        }
        __syncthreads();
        if (kq == 0) {
            #pragma unroll
            for (int j = 0; j < 8; ++j) {
                float s = part[0][j][cl] + part[1][j][cl]
                        + part[2][j][cl] + part[3][j][cl];
                W2[(size_t)(og * 8 + j) * C_ + c] = (bf16)s;
            }
        }
        if (cc == 0 && tid < 8) {
            float sb = 0.f;
            const float* rr = wo_w + (size_t)(og * 8 + tid) * C_;
            #pragma unroll 4
            for (int m = 0; m < C_; ++m) sb = fmaf(rr[m], wv_b[m], sb);
            b2[og * 8 + tid] = sb;
        }
    }
}

// ---------------------------------------------------------------------------
// K2 (fused v5, 16 waves): per block (b, pt): full-M GEMM over 128-px panel.
//   Bp[128 p][512 c] bf16 (128KB, swz, persistent; residual source)
//   Al[512 o][32 c]  bf16 (32KB, single-buffered, BK=32)
//   16 waves; wave (wm=wid>>1, wp=wid&1) owns 64o x 64p; acc[4][4] (64 VGPR).
//   Scores via MFMA on shared B frags (waves 0,1); in-register softmax;
//   out = bf16(x) + wo_b + s*(acc + b2).
// A issued 1 tile ahead (L2 cover), B 2 tiles ahead (HBM cover), even/odd regs.

__global__ __launch_bounds__(1024) void k_fused(const float* __restrict__ x,
                                                const bf16* __restrict__ W2,
                                                const float* __restrict__ b2,
                                                const float* __restrict__ wo_b,
                                                const bf16* __restrict__ Qkb,
                                                float* __restrict__ out) {
    // XCD swizzle (512 % 8 == 0 -> bijective)
    int id = blockIdx.x;
    int job = (id & 7) * 64 + (id >> 3);          // 0..511
    int b = job >> 5, pt = job & 31;
    int p0 = pt * 128;                            // 2 complete h-rows

    __shared__ __align__(128) unsigned char Bp[131072]; // [128 p][512 c] bf16 swz
    __shared__ __align__(128) unsigned char Al[32768];  // [512 o][32 c] bf16 swz

    int tid = threadIdx.x;
    int wid = tid >> 6, lane = tid & 63;
    int wm = wid >> 1, wp = wid & 1;

    // B-stage role: thread owns ONE pixel, 4 channels per tile
    int pg = tid & 127, cq = tid >> 7;            // pixel, c-quad (0..7)
    int fB = (pg & 63) << 4;                      // full-slot swizzle
    // A-stage role: 2 threads per row, 2x16B slots each
    int r0 = tid >> 1, sl = tid & 1;
    int fA = ((r0 >> 1) & 3) << 4;

    f32x4 acc[4][4] = {};
    f32x4 acc_q[4] = {};

    const float* xb = x + (size_t)b * C_ * HW + p0 + pg;

    bf16x8 ar[2];
    float bvA[4], bvB[4];

#define ISSUE_A(K0)                                                           \
    { _Pragma("unroll")                                                       \
      for (int q = 0; q < 2; ++q)                                            \
          ar[q] = *(const bf16x8*)(W2 + (size_t)r0 * C_ + (K0) + (sl*2+q)*8); }

#define ISSUE_B(K0, BV)                                                       \
    { _Pragma("unroll")                                                       \
      for (int i = 0; i < 4; ++i)                                            \
          BV[i] = xb[(size_t)((K0) + cq*4 + i) * HW]; }

#define STAGE_WRITE(K0, BV)                                                   \
    { _Pragma("unroll")                                                       \
      for (int q = 0; q < 2; ++q)                                            \
          *(bf16x8*)(&Al[r0*64 + ((((sl*2+q)*16)) ^ fA)]) = ar[q];            \
      bf16x4 bw;                                                              \
      _Pragma("unroll")                                                       \
      for (int i = 0; i < 4; ++i) bw[i] = (bf16)BV[i];                        \
      *(bf16x4*)(&Bp[pg*1024 + ((((K0)*2) + cq*8) ^ fB)]) = bw; }

#define MFMA_TILE(K0)                                                         \
    { int kb = (K0)*2 + ((lane>>4)<<4);                                       \
      bf16x8 bbf[4];                                                          \
      _Pragma("unroll")                                                       \
      for (int j = 0; j < 4; ++j) {                                          \
          int row = wp*64 + j*16 + (lane&15);                                 \
          bbf[j] = *(const bf16x8*)(&Bp[row*1024 + (kb ^ ((row&63)<<4))]);    \
      }                                                                       \
      __builtin_amdgcn_s_setprio(1);                                          \
      _Pragma("unroll")                                                       \
      for (int i = 0; i < 4; ++i) {                                          \
          int row = wm*64 + i*16 + (lane&15);                                 \
          bf16x8 av = *(const bf16x8*)(&Al[row*64 +                           \
                          (((lane>>4)<<4) ^ (((row>>1)&3)<<4))]);             \
          _Pragma("unroll")                                                   \
          for (int j = 0; j < 4; ++j)                                        \
              acc[i][j] = __builtin_amdgcn_mfma_f32_16x16x32_bf16(            \
                              av, bbf[j], acc[i][j], 0, 0, 0);                \
      }                                                                       \
      if (wm == 0) {                                                          \
          bf16x8 aq = *(const bf16x8*)(Qkb + ((size_t)b*16 + (lane&15))*C_    \
                                        + (K0) + ((lane>>4)<<3));             \
          _Pragma("unroll")                                                   \
          for (int j = 0; j < 4; ++j)                                        \
              acc_q[j] = __builtin_amdgcn_mfma_f32_16x16x32_bf16(             \
                             aq, bbf[j], acc_q[j], 0, 0, 0);                  \
      }                                                                       \
      __builtin_amdgcn_s_setprio(0); }

    // ---- prologue: A(0), B(0), B(1) in flight ----
    ISSUE_A(0);
    ISSUE_B(0,  bvA);
    ISSUE_B(32, bvB);

    #pragma unroll 1
    for (int tt = 0; tt < 8; ++tt) {
        int k0 = tt * 64;
        // ---- even tile (k0), consumes bvA ----
        STAGE_WRITE(k0, bvA);                     // compiler waits vmcnt for ar/bvA
        asm volatile("s_waitcnt lgkmcnt(0)" ::: "memory");
        __builtin_amdgcn_s_barrier();
        ISSUE_A(k0 + 32);                         // 1 tile ahead (L2)
        if (tt < 7) ISSUE_B(k0 + 64, bvA);        // 2 tiles ahead (HBM)
        MFMA_TILE(k0);
        __builtin_amdgcn_s_barrier();             // Al/Bp reads done
        // ---- odd tile (k0+32), consumes bvB ----
        STAGE_WRITE(k0 + 32, bvB);
        asm volatile("s_waitcnt lgkmcnt(0)" ::: "memory");
        __builtin_amdgcn_s_barrier();
        if (tt < 7) { ISSUE_A(k0 + 64); ISSUE_B(k0 + 96, bvB); }
        MFMA_TILE(k0 + 32);
        __builtin_amdgcn_s_barrier();
    }

    // ---- in-register softmax over w (64 px) on waves 0,1 ----
    float* s_lds = (float*)Al;                    // Al is dead now
    if (wm == 0) {
        float sm[4];
        #pragma unroll
        for (int r = 0; r < 4; ++r) {
            float m = fmaxf(fmaxf(acc_q[0][r], acc_q[1][r]),
                            fmaxf(acc_q[2][r], acc_q[3][r]));
            #pragma unroll
            for (int off = 1; off <= 8; off <<= 1) m = fmaxf(m, __shfl_xor(m, off));
            float s = 0.f;
            #pragma unroll
            for (int j = 0; j < 4; ++j) { acc_q[j][r] = __expf(acc_q[j][r] - m); s += acc_q[j][r]; }
            #pragma unroll
            for (int off = 1; off <= 8; off <<= 1) s += __shfl_xor(s, off);
            sm[r] = s;
        }
        f32x4 rcp;
        #pragma unroll
        for (int r = 0; r < 4; ++r) rcp[r] = 1.f / sm[r];
        #pragma unroll
        for (int j = 0; j < 4; ++j) {
            float sp = acc_q[j][0]*rcp[0] + acc_q[j][1]*rcp[1]
                     + acc_q[j][2]*rcp[2] + acc_q[j][3]*rcp[3];
            sp += __shfl_xor(sp, 16);             // add the other n-quad
            if (lane < 16) s_lds[wp*64 + j*16 + lane] = sp;
        }
    }
    __syncthreads();

    // ---- epilogue: out = bf16(x) + wo_b + s*(acc + b2); residual from Bp ----
    int r4 = (lane >> 4) << 2;
    int cl = lane & 15;
    #pragma unroll
    for (int j = 0; j < 4; ++j) {
        int pl = wp * 64 + j * 16 + cl;
        float sv = s_lds[pl];
        int fBp = (pl & 63) << 4;
        #pragma unroll
        for (int i = 0; i < 4; ++i) {
            int ob = wm * 64 + i * 16 + r4;
            f32x4 b2v = *(const f32x4*)(b2 + ob);
            f32x4 wbv = *(const f32x4*)(wo_b + ob);
            bf16x4 rx = *(const bf16x4*)(&Bp[pl*1024 + ((ob*2) ^ fBp)]);
            #pragma unroll
            for (int r = 0; r < 4; ++r) {
                size_t gi = ((size_t)b * C_ + ob + r) * HW + p0 + pl;
                out[gi] = (float)rx[r] + wbv[r] + sv * (acc[i][j][r] + b2v[r]);
            }
        }
    }
#undef ISSUE_A
#undef ISSUE_B
#undef STAGE_WRITE
#undef MFMA_TILE
}

// ---------------------------------------------------------------------------
extern "C" void kernel_launch(void* const* d_in, const int* in_sizes, int n_in,
                              void* d_out, int out_size, void* d_ws, size_t ws_size,
                              hipStream_t stream) {
    const float* x    = (const float*)d_in[0];
    const float* se   = (const float*)d_in[1];
    const float* wts  = (const float*)d_in[2];
    const float* wq_w = (const float*)d_in[3];
    const float* wq_b = (const float*)d_in[4];
    const float* wk_w = (const float*)d_in[5];
    // d_in[6] = wk_b: constant over softmax axis -> cancels, unused
    const float* wv_w = (const float*)d_in[7];
    const float* wv_b = (const float*)d_in[8];
    const float* wo_w = (const float*)d_in[9];
    const float* wo_b = (const float*)d_in[10];
    float* out = (float*)d_out;

    // workspace layout (<1MB)
    char* ws = (char*)d_ws;
    bf16*  Qkb = (bf16*) (ws + 0);          // 256KB [16][16][512], rows 8..15 zero
    bf16*  W2  = (bf16*) (ws + 262144);     // 512KB
    float* b2  = (float*)(ws + 786432);     // 2KB

    k_pre   <<<dim3(640), dim3(512),  0, stream>>>(se, wts, wq_w, wq_b, wk_w,
                                                   wo_w, wv_w, wv_b, Qkb, W2, b2);
    k_fused <<<dim3(512), dim3(1024), 0, stream>>>(x, W2, b2, wo_b, Qkb, out);
}

// Round 12
// 142.858 us; speedup vs baseline: 1.5940x; 1.5940x over previous
//
#include <hip/hip_runtime.h>
#include <hip/hip_bf16.h>

// Problem dims (fixed by reference setup)
#define B_   16
#define N_   8
#define C_   512
#define D_   768
#define HH   64
#define WW   64
#define HW   4096          // 64*64 pixels per batch

typedef __bf16 bf16;
typedef __attribute__((ext_vector_type(8))) __bf16 bf16x8;
typedef __attribute__((ext_vector_type(4))) __bf16 bf16x4;
typedef __attribute__((ext_vector_type(4))) float  f32x4;

// ---------------------------------------------------------------------------
// K_pre (single launch):
// Blocks 0..127  : (b,n): Q in-register (wave-per-c, shfl-reduce) -> Ql LDS;
//                  Qkf[b] = bf16((Ql·wk_w)/sqrt(768)) in MFMA-FRAGMENT order:
//                  elem(t,lane,el): lane = n | (((m>>3)&3)<<4), t=m>>5, el=m&7.
//                  Padding rows n+8 zeroed.
// Blocks 128..639: W2 = wo_w·wv_w (8 o x 64 c per block, 8-wave K-split) written
//                  in fragment order W2f[t][wm][i][lane][el]; b2 on cc==0.
__global__ __launch_bounds__(512) void k_pre(const float* __restrict__ se,
                                             const float* __restrict__ weights,
                                             const float* __restrict__ wq_w,
                                             const float* __restrict__ wq_b,
                                             const float* __restrict__ wk_w,
                                             const float* __restrict__ wo_w,
                                             const float* __restrict__ wv_w,
                                             const float* __restrict__ wv_b,
                                             bf16* __restrict__ Qkf,
                                             bf16* __restrict__ W2f,
                                             float* __restrict__ b2) {
    __shared__ __align__(16) unsigned char smem[12288];
    int tid = threadIdx.x;
    int blk = blockIdx.x;
    if (blk < 128) {
        int b = blk >> 3, n = blk & 7;
        float* we = (float*)smem;                     // [768]
        float* Ql = (float*)(smem + 3072);            // [512]
        float wt = weights[n];
        const float* se_row = se + (size_t)(b * N_ + n) * D_;
        for (int i = tid; i < D_; i += 512) we[i] = se_row[i] * wt;
        __syncthreads();
        int wid = tid >> 6, lane = tid & 63;
        f32x4 wer[3];
        #pragma unroll
        for (int k = 0; k < 3; ++k)
            wer[k] = *(const f32x4*)(we + k * 256 + lane * 4);
        int c0 = wid * 64;
        #pragma unroll 2
        for (int cc = 0; cc < 64; ++cc) {
            int c = c0 + cc;
            const float* row = wq_w + (size_t)c * D_ + lane * 4;
            float dot = 0.f;
            #pragma unroll
            for (int k = 0; k < 3; ++k) {
                f32x4 v = *(const f32x4*)(row + k * 256);
                dot += v[0]*wer[k][0] + v[1]*wer[k][1]
                     + v[2]*wer[k][2] + v[3]*wer[k][3];
            }
            #pragma unroll
            for (int off = 1; off <= 32; off <<= 1) dot += __shfl_xor(dot, off);
            if (lane == 0) Ql[c] = dot + wq_b[c];
        }
        __syncthreads();
        int m = tid;
        float a0 = 0.f, a1 = 0.f, a2 = 0.f, a3 = 0.f;
        #pragma unroll 2
        for (int o = 0; o < C_; o += 4) {
            a0 = fmaf(Ql[o + 0], wk_w[(size_t)(o + 0) * C_ + m], a0);
            a1 = fmaf(Ql[o + 1], wk_w[(size_t)(o + 1) * C_ + m], a1);
            a2 = fmaf(Ql[o + 2], wk_w[(size_t)(o + 2) * C_ + m], a2);
            a3 = fmaf(Ql[o + 3], wk_w[(size_t)(o + 3) * C_ + m], a3);
        }
        float val = ((a0 + a1) + (a2 + a3)) * 3.6084391824351615e-2f;
        int t = m >> 5, sl = (m >> 3) & 3, el = m & 7;
        size_t qb = (size_t)b * 8192 + (size_t)t * 512;
        Qkf[qb + (size_t)(n | (sl << 4)) * 8 + el]       = (bf16)val;
        Qkf[qb + (size_t)((n + 8) | (sl << 4)) * 8 + el] = (bf16)0.f;
    } else {
        int bb = blk - 128;                           // 0..511
        int og = bb >> 3, cc = bb & 7;                // 64 o-groups x 8 c-chunks
        int cl = tid & 63, kq = tid >> 6;             // 8 waves
        int kqq = kq & 3;
        int khalf = kq >> 2;
        int c  = cc * 64 + cl;
        const float* wo = wo_w + (size_t)og * 8 * C_; // uniform rows
        float a[8] = {};
        #pragma unroll 4
        for (int i = 0; i < 64; ++i) {
            int k = kqq * 128 + khalf * 64 + i;
            float v = wv_w[(size_t)k * C_ + c];       // coalesced
            #pragma unroll
            for (int j = 0; j < 8; ++j)
                a[j] = fmaf(wo[(size_t)j * C_ + k], v, a[j]);  // s_load
        }
        float (*part)[8][64] = (float(*)[8][64])smem;
        #pragma unroll
        for (int j = 0; j < 8; ++j) {
            if (khalf) part[kqq][j][cl] = a[j];
        }
        __syncthreads();
        if (khalf == 0) {
            #pragma unroll
            for (int j = 0; j < 8; ++j) part[kqq][j][cl] += a[j];
        }
        __syncthreads();
        if (kq == 0) {
            int t  = c >> 5;
            int ln = (((c >> 3) & 3) << 4);
            int el = c & 7;
            #pragma unroll
            for (int j = 0; j < 8; ++j) {
                float s = part[0][j][cl] + part[1][j][cl]
                        + part[2][j][cl] + part[3][j][cl];
                int o = og * 8 + j;
                W2f[(size_t)t * 16384 + (o >> 7) * 4096 + ((o >> 4) & 7) * 512
                    + (size_t)((o & 15) | ln) * 8 + el] = (bf16)s;
            }
        }
        if (cc == 0 && tid < 8) {
            float sb = 0.f;
            const float* rr = wo_w + (size_t)(og * 8 + tid) * C_;
            #pragma unroll 4
            for (int m = 0; m < C_; ++m) sb = fmaf(rr[m], wv_b[m], sb);
            b2[og * 8 + tid] = sb;
        }
    }
}

// ---------------------------------------------------------------------------
// K2 (fused v6): per block (b, pt): full-M GEMM over 128-px panel.
//   Bp[128 p][512 c] bf16 (128KB, swz, persistent; residual source).
//   NO A-tile in LDS: A fragments loaded straight from W2f (fragment-order,
//   fully coalesced 1KB/instr, L2-hot) into registers. 16 tiles of BK=32,
//   ONE barrier per tile (persistence removes the WAR barrier).
//   B reg-staged 2 tiles ahead (HBM cover), static even/odd buffers.
__global__ __launch_bounds__(512, 2) void k_fused(const float* __restrict__ x,
                                                  const bf16* __restrict__ W2f,
                                                  const float* __restrict__ b2,
                                                  const float* __restrict__ wo_b,
                                                  const bf16* __restrict__ Qkf,
                                                  float* __restrict__ out) {
    // XCD swizzle (512 % 8 == 0 -> bijective)
    int id = blockIdx.x;
    int job = (id & 7) * 64 + (id >> 3);          // 0..511
    int b = job >> 5, pt = job & 31;
    int p0 = pt * 128;                            // 2 complete h-rows

    __shared__ __align__(128) unsigned char Bp[131072]; // [128 p][512 c] bf16 swz
    __shared__ float s_lds[128];

    int tid = threadIdx.x;
    int wid = tid >> 6, lane = tid & 63;
    int wm = wid >> 1, wp = wid & 1;

    int pg = tid & 127, cg = tid >> 7;            // B-stage: pixel, c-octet
    int fB = (pg & 63) << 4;

    f32x4 acc[8][4] = {};
    f32x4 acc_q[4] = {};

    const float* xb = x + (size_t)b * C_ * HW + p0 + pg;
    const bf16* Wb  = W2f + wm * 4096 + (size_t)lane * 8;
    const bf16* Qb  = Qkf + (size_t)b * 8192 + (size_t)lane * 8;

    float bvA[8], bvB[8];
    bf16x8 av[8];
    bf16x8 aq = {};

#define IB(T, BV)                                                             \
    { _Pragma("unroll")                                                       \
      for (int i = 0; i < 8; ++i)                                            \
          BV[i] = xb[(size_t)((T)*32 + cg*8 + i) * HW]; }

#define SW(T, BV)                                                             \
    { bf16x8 bw;                                                              \
      _Pragma("unroll")                                                       \
      for (int i = 0; i < 8; ++i) bw[i] = (bf16)BV[i];                        \
      *(bf16x8*)(&Bp[pg*1024 + ((((T)*64) + cg*16) ^ fB)]) = bw; }

#define IA(T)                                                                 \
    { _Pragma("unroll")                                                       \
      for (int i = 0; i < 8; ++i)                                            \
          av[i] = *(const bf16x8*)(Wb + (size_t)(T)*16384 + i*512);           \
      if (wm == 0) aq = *(const bf16x8*)(Qb + (size_t)(T)*512); }

#define MT(T)                                                                 \
    { int kb = (T)*64 + ((lane>>4)<<4);                                       \
      bf16x8 bbf[4];                                                          \
      _Pragma("unroll")                                                       \
      for (int j = 0; j < 4; ++j) {                                          \
          int row = wp*64 + j*16 + (lane&15);                                 \
          bbf[j] = *(const bf16x8*)(&Bp[row*1024 + (kb ^ ((row&63)<<4))]);    \
      }                                                                       \
      __builtin_amdgcn_s_setprio(1);                                          \
      _Pragma("unroll")                                                       \
      for (int i = 0; i < 8; ++i)                                            \
          _Pragma("unroll")                                                   \
          for (int j = 0; j < 4; ++j)                                        \
              acc[i][j] = __builtin_amdgcn_mfma_f32_16x16x32_bf16(            \
                              av[i], bbf[j], acc[i][j], 0, 0, 0);             \
      if (wm == 0) {                                                          \
          _Pragma("unroll")                                                   \
          for (int j = 0; j < 4; ++j)                                        \
              acc_q[j] = __builtin_amdgcn_mfma_f32_16x16x32_bf16(             \
                             aq, bbf[j], acc_q[j], 0, 0, 0);                  \
      }                                                                       \
      __builtin_amdgcn_s_setprio(0); }

    // ---- prologue: Bp(0) staged; B(1) in bvB, B(2) in flight to bvA ----
    IB(0, bvA); IB(1, bvB);
    SW(0, bvA);                                   // waits bvA loads
    IB(2, bvA);
    asm volatile("s_waitcnt lgkmcnt(0)" ::: "memory");
    __builtin_amdgcn_s_barrier();

    // ---- main loop: 16 tiles, 2 per iteration (static even/odd buffers) ----
    #pragma unroll 1
    for (int tt = 0; tt < 8; ++tt) {
        int t0 = tt * 2, t1 = t0 + 1;
        // tile t0 (even): stage odd tile t0+1 from bvB, refill bvB
        SW(t0 + 1, bvB);
        if (t0 + 3 <= 15) IB(t0 + 3, bvB);
        IA(t0);
        asm volatile("s_waitcnt lgkmcnt(0)" ::: "memory");
        __builtin_amdgcn_s_barrier();
        MT(t0);
        // tile t1 (odd): stage even tile t1+1 from bvA, refill bvA
        if (t1 + 1 <= 15) SW(t1 + 1, bvA);
        if (t1 + 3 <= 15) IB(t1 + 3, bvA);
        IA(t1);
        asm volatile("s_waitcnt lgkmcnt(0)" ::: "memory");
        __builtin_amdgcn_s_barrier();
        MT(t1);
    }

    // ---- in-register softmax over w (64 px) on waves 0,1 ----
    if (wm == 0) {
        float sm[4];
        #pragma unroll
        for (int r = 0; r < 4; ++r) {
            float m = fmaxf(fmaxf(acc_q[0][r], acc_q[1][r]),
                            fmaxf(acc_q[2][r], acc_q[3][r]));
            #pragma unroll
            for (int off = 1; off <= 8; off <<= 1) m = fmaxf(m, __shfl_xor(m, off));
            float s = 0.f;
            #pragma unroll
            for (int j = 0; j < 4; ++j) { acc_q[j][r] = __expf(acc_q[j][r] - m); s += acc_q[j][r]; }
            #pragma unroll
            for (int off = 1; off <= 8; off <<= 1) s += __shfl_xor(s, off);
            sm[r] = s;
        }
        f32x4 rcp;
        #pragma unroll
        for (int r = 0; r < 4; ++r) rcp[r] = 1.f / sm[r];
        #pragma unroll
        for (int j = 0; j < 4; ++j) {
            float sp = acc_q[j][0]*rcp[0] + acc_q[j][1]*rcp[1]
                     + acc_q[j][2]*rcp[2] + acc_q[j][3]*rcp[3];
            sp += __shfl_xor(sp, 16);             // add the other n-quad
            if (lane < 16) s_lds[wp*64 + j*16 + lane] = sp;
        }
    }
    __syncthreads();

    // ---- epilogue: out = bf16(x) + wo_b + s*(acc + b2); residual from Bp ----
    int r4 = (lane >> 4) << 2;
    int cl = lane & 15;
    #pragma unroll
    for (int j = 0; j < 4; ++j) {
        int pl = wp * 64 + j * 16 + cl;
        float sv = s_lds[pl];
        int fBp = (pl & 63) << 4;
        #pragma unroll
        for (int i = 0; i < 8; ++i) {
            int ob = wm * 128 + i * 16 + r4;
            f32x4 b2v = *(const f32x4*)(b2 + ob);
            f32x4 wbv = *(const f32x4*)(wo_b + ob);
            bf16x4 rx = *(const bf16x4*)(&Bp[pl*1024 + ((ob*2) ^ fBp)]);
            #pragma unroll
            for (int r = 0; r < 4; ++r) {
                size_t gi = ((size_t)b * C_ + ob + r) * HW + p0 + pl;
                out[gi] = (float)rx[r] + wbv[r] + sv * (acc[i][j][r] + b2v[r]);
            }
        }
    }
#undef IB
#undef SW
#undef IA
#undef MT
}

// ---------------------------------------------------------------------------
extern "C" void kernel_launch(void* const* d_in, const int* in_sizes, int n_in,
                              void* d_out, int out_size, void* d_ws, size_t ws_size,
                              hipStream_t stream) {
    const float* x    = (const float*)d_in[0];
    const float* se   = (const float*)d_in[1];
    const float* wts  = (const float*)d_in[2];
    const float* wq_w = (const float*)d_in[3];
    const float* wq_b = (const float*)d_in[4];
    const float* wk_w = (const float*)d_in[5];
    // d_in[6] = wk_b: constant over softmax axis -> cancels, unused
    const float* wv_w = (const float*)d_in[7];
    const float* wv_b = (const float*)d_in[8];
    const float* wo_w = (const float*)d_in[9];
    const float* wo_b = (const float*)d_in[10];
    float* out = (float*)d_out;

    // workspace layout (<1MB)
    char* ws = (char*)d_ws;
    bf16*  Qkf = (bf16*) (ws + 0);          // 256KB [16 b][16 t][64 lane][8] frag-order
    bf16*  W2f = (bf16*) (ws + 262144);     // 512KB [16 t][4 wm][8 i][64 lane][8]
    float* b2  = (float*)(ws + 786432);     // 2KB

    k_pre   <<<dim3(640), dim3(512), 0, stream>>>(se, wts, wq_w, wq_b, wk_w,
                                                  wo_w, wv_w, wv_b, Qkf, W2f, b2);
    k_fused <<<dim3(512), dim3(512), 0, stream>>>(x, W2f, b2, wo_b, Qkf, out);
}